// Round 5
// baseline (1003.100 us; speedup 1.0000x reference)
//
#include <hip/hip_runtime.h>
#include <hip/hip_bf16.h>
#include <stdint.h>

typedef __bf16 bf16x8 __attribute__((ext_vector_type(8)));
typedef float f32x4 __attribute__((ext_vector_type(4)));
typedef unsigned short u16x8 __attribute__((ext_vector_type(8)));

#define DEVINL static __device__ __forceinline__

// f32 -> bf16 round-to-nearest-even (finite values)
DEVINL unsigned short f2bf(float f) {
  unsigned u = __builtin_bit_cast(unsigned, f);
  unsigned r = (u + 0x7FFFu + ((u >> 16) & 1u)) >> 16;
  return (unsigned short)r;
}
DEVINL float bf2f(unsigned short u) {
  return __builtin_bit_cast(float, ((unsigned)u) << 16);
}

DEVINL void gload_lds16(const unsigned short* g, unsigned short* l) {
  __builtin_amdgcn_global_load_lds(
      (const __attribute__((address_space(1))) void*)g,
      (__attribute__((address_space(3))) void*)l, 16, 0, 0);
}

// ---------------- embed: h = tok_emb[x] + pos_emb[s], store bf16 ----------
__global__ __launch_bounds__(256) void embed_kernel(
    const int* __restrict__ x, const float* __restrict__ tok,
    const float* __restrict__ pos, unsigned short* __restrict__ hb)
{
  const int bs = blockIdx.x;           // 0..8191  (b*2048 + s)
  const int s  = bs & 2047;
  const long trow = (long)x[bs] * 1024;
  const int d = threadIdx.x * 4;
  const float4 t = *(const float4*)(tok + trow + d);
  const float4 p = *(const float4*)(pos + (long)s * 1024 + d);
  ushort4 o;
  o.x = f2bf(t.x + p.x);
  o.y = f2bf(t.y + p.y);
  o.z = f2bf(t.z + p.z);
  o.w = f2bf(t.w + p.w);
  *(ushort4*)(hb + (long)bs * 1024 + d) = o;
}

// ---------------- f32 -> bf16 convert (weights) ---------------------------
__global__ __launch_bounds__(256) void cvt_kernel(
    const float* __restrict__ in, unsigned short* __restrict__ out, int n4)
{
  for (int i = blockIdx.x * blockDim.x + threadIdx.x; i < n4;
       i += gridDim.x * blockDim.x) {
    float4 v = ((const float4*)in)[i];
    ushort4 o;
    o.x = f2bf(v.x); o.y = f2bf(v.y); o.z = f2bf(v.z); o.w = f2bf(v.w);
    ((ushort4*)out)[i] = o;
  }
}

// ---------------- GEMM: C[m,n] = scale * sum_k A[m,k]*B[n,k] + bias[n] ----
// (m97-structure 128x128 kernel — used for QKV / scores / PV)
template<int OUTMODE>
__global__ __launch_bounds__(256) void gemm_bt(
    const unsigned short* __restrict__ A, const unsigned short* __restrict__ B,
    void* __restrict__ Cout, const float* __restrict__ bias,
    float scale, int M, int N, int K,
    long sA, long sB, long sC, int Mb, long tStride)
{
  __shared__ __align__(16) unsigned short lA[128 * 32];
  __shared__ __align__(16) unsigned short lB[128 * 32];
  const int tid = threadIdx.x, wid = tid >> 6, lane = tid & 63;
  A += (long)blockIdx.z * sA;
  B += (long)blockIdx.z * sB;
  const int bm = blockIdx.y * 128, bn = blockIdx.x * 128;

  const int c0 = wid * 64 + lane, c1 = c0 + 256;
  const unsigned short* gA0 = A + (long)(bm + (c0 >> 2)) * K + (c0 & 3) * 8;
  const unsigned short* gA1 = A + (long)(bm + (c1 >> 2)) * K + (c1 & 3) * 8;
  const unsigned short* gB0 = B + (long)(bn + (c0 >> 2)) * K + (c0 & 3) * 8;
  const unsigned short* gB1 = B + (long)(bn + (c1 >> 2)) * K + (c1 & 3) * 8;
  unsigned short* lA0 = lA + wid * 512;
  unsigned short* lA1 = lA + 2048 + wid * 512;
  unsigned short* lB0 = lB + wid * 512;
  unsigned short* lB1 = lB + 2048 + wid * 512;

  const int wr = (wid >> 1) * 64, wc = (wid & 1) * 64;
  const int lr = lane & 15, lk = (lane >> 4) * 8;

  f32x4 acc[4][4] = {};
  const int nk = K >> 5;
  for (int kt = 0; kt < nk; ++kt) {
    const int ko = kt << 5;
    gload_lds16(gA0 + ko, lA0);
    gload_lds16(gA1 + ko, lA1);
    gload_lds16(gB0 + ko, lB0);
    gload_lds16(gB1 + ko, lB1);
    __syncthreads();
    bf16x8 af[4], bg[4];
#pragma unroll
    for (int m = 0; m < 4; ++m)
      af[m] = *(const bf16x8*)(const void*)(lA + (wr + m * 16 + lr) * 32 + lk);
#pragma unroll
    for (int n = 0; n < 4; ++n)
      bg[n] = *(const bf16x8*)(const void*)(lB + (wc + n * 16 + lr) * 32 + lk);
#pragma unroll
    for (int m = 0; m < 4; ++m)
#pragma unroll
      for (int n = 0; n < 4; ++n)
        acc[m][n] = __builtin_amdgcn_mfma_f32_16x16x32_bf16(af[m], bg[n],
                                                            acc[m][n], 0, 0, 0);
    __syncthreads();
  }

  const int r0 = bm + wr + ((lane >> 4) << 2);
  const int cbase = bn + wc + lr;
#pragma unroll
  for (int n = 0; n < 4; ++n) {
    const int col = cbase + n * 16;
    const float bv = bias ? bias[col] : 0.f;
#pragma unroll
    for (int m = 0; m < 4; ++m) {
      const int row0 = r0 + m * 16;
      if (OUTMODE == 2) {
        float* C = (float*)Cout + (long)blockIdx.z * sC;
#pragma unroll
        for (int i = 0; i < 4; ++i)
          C[(long)(row0 + i) * N + col] = acc[m][n][i] * scale + bv;
      } else if (OUTMODE == 0) {
        unsigned short* C = (unsigned short*)Cout + (long)blockIdx.z * sC;
#pragma unroll
        for (int i = 0; i < 4; ++i)
          C[(long)(row0 + i) * N + col] = f2bf(acc[m][n][i] * scale + bv);
      } else {  // transposed write Vt[b][col][srow]
        unsigned short* C = (unsigned short*)Cout;
        const int b = row0 / Mb;
        const int srow = row0 - b * Mb;
        ushort4 o;
        o.x = f2bf(acc[m][n][0] * scale + bv);
        o.y = f2bf(acc[m][n][1] * scale + bv);
        o.z = f2bf(acc[m][n][2] * scale + bv);
        o.w = f2bf(acc[m][n][3] * scale + bv);
        *(ushort4*)(C + (long)b * tStride + (long)col * Mb + srow) = o;
      }
    }
  }
}

// ---------------- row softmax in place over 2048 bf16 ---------------------
__global__ __launch_bounds__(256) void softmax_kernel(unsigned short* __restrict__ S)
{
  unsigned short* row = S + (long)blockIdx.x * 2048;
  const int t = threadIdx.x, lane = t & 63, wid = t >> 6;
  __shared__ float redm[4], reds[4];
  u16x8 raw = ((const u16x8*)row)[t];
  float v[8];
#pragma unroll
  for (int j = 0; j < 8; ++j) v[j] = bf2f(raw[j]);
  float mx = v[0];
#pragma unroll
  for (int j = 1; j < 8; ++j) mx = fmaxf(mx, v[j]);
#pragma unroll
  for (int off = 32; off; off >>= 1) mx = fmaxf(mx, __shfl_xor(mx, off, 64));
  if (lane == 0) redm[wid] = mx;
  __syncthreads();
  mx = fmaxf(fmaxf(redm[0], redm[1]), fmaxf(redm[2], redm[3]));
  float s = 0.f;
#pragma unroll
  for (int j = 0; j < 8; ++j) { v[j] = __expf(v[j] - mx); s += v[j]; }
#pragma unroll
  for (int off = 32; off; off >>= 1) s += __shfl_xor(s, off, 64);
  if (lane == 0) reds[wid] = s;
  __syncthreads();
  s = reds[0] + reds[1] + reds[2] + reds[3];
  const float inv = 1.f / s;
  u16x8 o;
#pragma unroll
  for (int j = 0; j < 8; ++j) o[j] = f2bf(v[j] * inv);
  ((u16x8*)row)[t] = o;
}

// ================= FC GEMM v3: occupancy-first 128x256 ====================
// C[8192][32000] = A[8192][1024] @ B[32000][1024]^T + bias, f32 out.
// 512 thr = 8 waves (2M x 4N), per-wave 64x64 -> acc = 64 regs.
// __launch_bounds__(512,4) caps regs at 128/wave -> 2 blocks/CU = 16 waves
// (m97 mechanism: cross-block TLP hides barrier drains; no hand pipeline).
// BK=32 double-buffered LDS 48 KB; bank swizzle slot ^= (row>>1)&3 applied
// storage-side via inverse-swizzled global source (rule #21).
__global__ __launch_bounds__(512, 4) void gemm_fc2(
    const unsigned short* __restrict__ A, const unsigned short* __restrict__ B,
    float* __restrict__ C, const float* __restrict__ bias)
{
  constexpr int N = 32000;
  __shared__ __align__(16) unsigned short shA[2][128 * 32];  // 16 KB
  __shared__ __align__(16) unsigned short shB[2][256 * 32];  // 32 KB
  const int tid = threadIdx.x, wid = tid >> 6, lane = tid & 63;
  const int wm = wid >> 2, wn = wid & 3;
  const int lr = lane & 15, q = lane >> 4;

  // XCD-chunk swizzle: 8000 wgs, 1000/XCD; consecutive swz share the B panel
  const int f = blockIdx.x;
  const int swz = (f & 7) * 1000 + (f >> 3);
  const int bn = swz / 64, bm = swz % 64;
  const long bmRow = (long)bm * 128, bnRow = (long)bn * 256;

  // staging: thread stages 16B A + 2x16B B per K-step. Linear LDS offset o:
  // row = o/64, slot = (o&63)>>4; global col-slot = slot ^ ((row>>1)&3).
  const int oA = tid * 16;
  const int rA = oA >> 6;
  const int slA = (((oA & 63) >> 4) ^ ((rA >> 1) & 3)) << 4;
  const char* gA = (const char*)A + (bmRow + rA) * 2048 + slA;
  const int oB1 = oA + 8192;
  const int rB0 = rA, rB1 = oB1 >> 6;
  const int slB0 = slA;
  const int slB1 = (((oB1 & 63) >> 4) ^ ((rB1 >> 1) & 3)) << 4;
  const char* gB0 = (const char*)B + (bnRow + rB0) * 2048 + slB0;
  const char* gB1 = (const char*)B + (bnRow + rB1) * 2048 + slB1;
  unsigned short* dA = &shA[0][0] + tid * 8;
  unsigned short* dB0 = &shB[0][0] + tid * 8;
  unsigned short* dB1 = &shB[0][0] + 4096 + tid * 8;

  // fragment read offsets (bytes), swizzle-XOR folded in:
  // row = base+lr with base%16==0  =>  (row>>1)&3 == (lr>>1)&3
  const int xsl = (q ^ ((lr >> 1) & 3)) << 4;
  const int aoff = (wm * 64 + lr) * 64 + xsl;
  const int boff = (wn * 64 + lr) * 64 + xsl;

  f32x4 acc[4][4] = {};

  // prologue: stage k=0 into buf0
  gload_lds16((const unsigned short*)gA, dA);
  gload_lds16((const unsigned short*)gB0, dB0);
  gload_lds16((const unsigned short*)gB1, dB1);
  __syncthreads();

  for (int k = 0; k < 32; ++k) {
    const int buf = k & 1;
    if (k < 31) {  // prefetch k+1 into buf^1
      const long ko = (long)(k + 1) * 64;
      const int bo = (buf ^ 1) * 4096;  // elems: A half 4096, B half 8192
      gload_lds16((const unsigned short*)(gA + ko), dA + bo);
      gload_lds16((const unsigned short*)(gB0 + ko), dB0 + 2 * bo);
      gload_lds16((const unsigned short*)(gB1 + ko), dB1 + 2 * bo);
    }
    const char* pA = (const char*)&shA[buf][0];
    const char* pB = (const char*)&shB[buf][0];
    bf16x8 af[4], bg[4];
#pragma unroll
    for (int m = 0; m < 4; ++m)
      af[m] = *(const bf16x8*)(pA + aoff + m * 1024);
#pragma unroll
    for (int n = 0; n < 4; ++n)
      bg[n] = *(const bf16x8*)(pB + boff + n * 1024);
#pragma unroll
    for (int m = 0; m < 4; ++m)
#pragma unroll
      for (int n = 0; n < 4; ++n)
        acc[m][n] = __builtin_amdgcn_mfma_f32_16x16x32_bf16(af[m], bg[n],
                                                            acc[m][n], 0, 0, 0);
    __syncthreads();
  }

  // epilogue
  float bv[4];
#pragma unroll
  for (int n = 0; n < 4; ++n) bv[n] = bias[bnRow + wn * 64 + n * 16 + lr];
#pragma unroll
  for (int m = 0; m < 4; ++m) {
    const long row0 = bmRow + wm * 64 + m * 16 + q * 4;
#pragma unroll
    for (int i = 0; i < 4; ++i) {
      float* orow = C + (row0 + i) * (long)N;
#pragma unroll
      for (int n = 0; n < 4; ++n)
        orow[bnRow + wn * 64 + n * 16 + lr] = acc[m][n][i] + bv[n];
    }
  }
}

// ---------------------------------------------------------------------------
extern "C" void kernel_launch(void* const* d_in, const int* in_sizes, int n_in,
                              void* d_out, int out_size, void* d_ws, size_t ws_size,
                              hipStream_t stream)
{
  const int*   x   = (const int*)d_in[0];
  const float* tok = (const float*)d_in[1];
  const float* pos = (const float*)d_in[2];
  const float* Wq  = (const float*)d_in[3];
  const float* bq  = (const float*)d_in[4];
  const float* Wk  = (const float*)d_in[5];
  const float* bk  = (const float*)d_in[6];
  const float* Wv  = (const float*)d_in[7];
  const float* bv  = (const float*)d_in[8];
  const float* Wfc = (const float*)d_in[9];
  const float* bfc = (const float*)d_in[10];
  float* out = (float*)d_out;

  char* ws = (char*)d_ws;
  unsigned short* hb   = (unsigned short*)(ws);              // 16 MB  [8192][1024]
  unsigned short* Wqb  = (unsigned short*)(ws + 16777216);   // 2 MB
  unsigned short* Wkb  = (unsigned short*)(ws + 18874368);   // 2 MB
  unsigned short* Wvb  = (unsigned short*)(ws + 20971520);   // 2 MB
  unsigned short* Wfcb = (unsigned short*)(ws + 23068672);   // 62.5 MB [32000][1024]
  unsigned short* Qb   = (unsigned short*)(ws + 88604672);   // 16 MB
  unsigned short* Kb   = (unsigned short*)(ws + 105381888);  // 16 MB
  unsigned short* Vt   = (unsigned short*)(ws + 122159104);  // 16 MB [4][1024][2048]
  unsigned short* Sc   = (unsigned short*)(ws + 138936320);  // 32 MB [4][2048][2048]
  unsigned short* AO   = hb;  // alias: h dead after QKV

  embed_kernel<<<8192, 256, 0, stream>>>(x, tok, pos, hb);
  cvt_kernel<<<512, 256, 0, stream>>>(Wq, Wqb, 1024 * 1024 / 4);
  cvt_kernel<<<512, 256, 0, stream>>>(Wk, Wkb, 1024 * 1024 / 4);
  cvt_kernel<<<512, 256, 0, stream>>>(Wv, Wvb, 1024 * 1024 / 4);
  cvt_kernel<<<2048, 256, 0, stream>>>(Wfc, Wfcb, 32000 * 1024 / 4);

  dim3 blk(256);
  gemm_bt<0><<<dim3(8, 64, 1), blk, 0, stream>>>(hb, Wqb, Qb, bq, 1.f,
      8192, 1024, 1024, 0, 0, 0, 0, 0);
  gemm_bt<0><<<dim3(8, 64, 1), blk, 0, stream>>>(hb, Wkb, Kb, bk, 1.f,
      8192, 1024, 1024, 0, 0, 0, 0, 0);
  gemm_bt<1><<<dim3(8, 64, 1), blk, 0, stream>>>(hb, Wvb, Vt, bv, 1.f,
      8192, 1024, 1024, 0, 0, 0, 2048, 1024L * 2048);
  gemm_bt<0><<<dim3(16, 16, 4), blk, 0, stream>>>(Qb, Kb, Sc, nullptr, 0.03125f,
      2048, 2048, 1024, 2048L * 1024, 2048L * 1024, 2048L * 2048, 0, 0);
  softmax_kernel<<<8192, 256, 0, stream>>>(Sc);
  gemm_bt<0><<<dim3(8, 16, 4), blk, 0, stream>>>(Sc, Vt, AO, nullptr, 1.f,
      2048, 1024, 2048, 2048L * 2048, 1024L * 2048, 2048L * 1024, 0, 0);
  // logits = AO @ Wfc^T + bfc  (occupancy-first 128x256 kernel, 2 blocks/CU)
  gemm_fc2<<<dim3(8000), dim3(512), 0, stream>>>(AO, Wfcb, out, bfc);
}